// Round 1
// baseline (2960.894 us; speedup 1.0000x reference)
//
#include <hip/hip_runtime.h>
#include <math.h>

#define NB   8
#define NC   256
#define ND   64
#define NPIX 4096

// ---------------------------------------------------------------------------
// conv3x3, SAME padding. grid (64 rows h, B, Cout/64), block 256.
// layoutA=1: out[b][p][64]  (d-contiguous, for q/k, Cout=64)
// layoutA=0: out[b][co][p]  (p-contiguous, for v, Cout=256)
// ---------------------------------------------------------------------------
__global__ __launch_bounds__(256) void conv3x3_k(
    const float* __restrict__ x, const float* __restrict__ Wt,
    const float* __restrict__ bias, float* __restrict__ out, int layoutA)
{
    const int h   = blockIdx.x;
    const int b   = blockIdx.y;
    const int co0 = blockIdx.z * 64;
    const int t   = threadIdx.x;
    const int tw  = t & 15;   // pixel group: w = 4*tw..+3
    const int tc  = t >> 4;   // co group:   co = tc*4..+3

    __shared__ float xs[3][8][68];   // [row r][ci][1+col], cols 0 & 65 are zero pad
    __shared__ float ws[64][100];    // [co][ci*12 + k], k<9 used (b128-friendly)

    float acc[4][4]; // [i=pixel][j=co]
    #pragma unroll
    for (int i = 0; i < 4; i++)
        #pragma unroll
        for (int j = 0; j < 4; j++) acc[i][j] = 0.f;

    if (t < 24) { int r = t % 3, ci = t / 3; xs[r][ci][0] = 0.f; xs[r][ci][65] = 0.f; }

    for (int ci0 = 0; ci0 < NC; ci0 += 8) {
        __syncthreads(); // prev chunk compute done before overwriting LDS
        // stage x: rows h-1..h+1, 8 input channels, 64 cols (1536 elems)
        for (int idx = t; idx < 1536; idx += 256) {
            int col = idx & 63;
            int pr  = idx >> 6;             // 0..23
            int r = pr % 3, ci = pr / 3;
            int hs = h + r - 1;
            float val = 0.f;
            if (hs >= 0 && hs < 64)
                val = x[(((size_t)b * NC + ci0 + ci) * 64 + hs) * 64 + col];
            xs[r][ci][1 + col] = val;
        }
        // stage weights: 64 co x 8 ci x 9 (4608 elems)
        for (int idx = t; idx < 4608; idx += 256) {
            int co = idx / 72, rem = idx - co * 72;
            int ci = rem / 9,  kk  = rem - ci * 9;
            ws[co][ci * 12 + kk] = Wt[((size_t)(co0 + co) * NC + ci0 + ci) * 9 + kk];
        }
        __syncthreads();
        #pragma unroll
        for (int ci = 0; ci < 8; ci++) {
            float xv[18];
            #pragma unroll
            for (int r = 0; r < 3; r++)
                #pragma unroll
                for (int c = 0; c < 6; c++)
                    xv[r * 6 + c] = xs[r][ci][4 * tw + c];
            #pragma unroll
            for (int j = 0; j < 4; j++) {
                const float* wr = &ws[tc * 4 + j][ci * 12];
                #pragma unroll
                for (int i = 0; i < 4; i++) {
                    float a = acc[i][j];
                    #pragma unroll
                    for (int r = 0; r < 3; r++)
                        #pragma unroll
                        for (int dx = 0; dx < 3; dx++)
                            a = fmaf(wr[r * 3 + dx], xv[r * 6 + i + dx], a);
                    acc[i][j] = a;
                }
            }
        }
    }

    float bj[4];
    #pragma unroll
    for (int j = 0; j < 4; j++) bj[j] = bias[co0 + tc * 4 + j];

    const int p0 = h * 64 + tw * 4;
    if (layoutA) {
        #pragma unroll
        for (int i = 0; i < 4; i++) {
            float4 o = make_float4(acc[i][0] + bj[0], acc[i][1] + bj[1],
                                   acc[i][2] + bj[2], acc[i][3] + bj[3]);
            *(float4*)&out[((size_t)b * NPIX + p0 + i) * 64 + tc * 4] = o;
        }
    } else {
        #pragma unroll
        for (int j = 0; j < 4; j++) {
            float bb = bj[j];
            float4 o = make_float4(acc[0][j] + bb, acc[1][j] + bb,
                                   acc[2][j] + bb, acc[3][j] + bb);
            *(float4*)&out[((size_t)b * NC + co0 + tc * 4 + j) * NPIX + p0] = o;
        }
    }
}

// ---------------------------------------------------------------------------
// Fused attention: out[b,c,m] = (sum_n exp(q_m.k_n - 30) * v[c,n]) / l_m + x[b,c,m]
// grid (N/64, B), block 256. Never materializes the NxN matrix.
// thread (tm = t>>4, tn = t&15): QK tile 4m x 4n; PV acc 4m x 16c (x4 c-chunks).
// ---------------------------------------------------------------------------
__global__ __launch_bounds__(256) void attn_k(
    const float* __restrict__ q, const float* __restrict__ k,
    const float* __restrict__ v, const float* __restrict__ x,
    float* __restrict__ out)
{
    const int b  = blockIdx.y;
    const int m0 = blockIdx.x * 64;
    const int t  = threadIdx.x;
    const int tn = t & 15;
    const int tm = t >> 4;

    __shared__ float qs[64][68];
    __shared__ float ks[64][68];
    __shared__ float ps[64][68];
    __shared__ float vs[64][68];
    __shared__ float red[64][17];
    __shared__ float invl[64];

    for (int idx = t; idx < 4096; idx += 256) {
        int m = idx >> 6, d = idx & 63;
        qs[m][d] = q[((size_t)b * NPIX + m0 + m) * ND + d];
    }

    float acc[4][16];
    #pragma unroll
    for (int i = 0; i < 4; i++)
        #pragma unroll
        for (int j = 0; j < 16; j++) acc[i][j] = 0.f;
    float lsum[4] = {0.f, 0.f, 0.f, 0.f};

    for (int n0 = 0; n0 < NPIX; n0 += 64) {
        __syncthreads(); // prev iter's ps/ks consumers done
        for (int idx = t; idx < 4096; idx += 256) {
            int n = idx >> 6, d = idx & 63;
            ks[n][d] = k[((size_t)b * NPIX + n0 + n) * ND + d];
        }
        __syncthreads();

        // S = q_tile . k_tile^T  (4x4 per thread, lane-rotated d to dodge conflicts)
        float s[4][4];
        #pragma unroll
        for (int i = 0; i < 4; i++)
            #pragma unroll
            for (int j = 0; j < 4; j++) s[i][j] = 0.f;

        #pragma unroll 4
        for (int dd = 0; dd < 16; dd++) {
            int d4 = ((dd + tn) & 15) << 2;
            float4 qv[4], kv[4];
            #pragma unroll
            for (int ii = 0; ii < 4; ii++) qv[ii] = *(const float4*)&qs[tm * 4 + ii][d4];
            #pragma unroll
            for (int jj = 0; jj < 4; jj++) kv[jj] = *(const float4*)&ks[tn * 4 + jj][d4];
            #pragma unroll
            for (int ii = 0; ii < 4; ii++)
                #pragma unroll
                for (int jj = 0; jj < 4; jj++) {
                    float a = s[ii][jj];
                    a = fmaf(qv[ii].x, kv[jj].x, a);
                    a = fmaf(qv[ii].y, kv[jj].y, a);
                    a = fmaf(qv[ii].z, kv[jj].z, a);
                    a = fmaf(qv[ii].w, kv[jj].w, a);
                    s[ii][jj] = a;
                }
        }

        // p = exp(s - 30); fp32 range is safe (logits ~N(0,64), need >118 to overflow)
        #pragma unroll
        for (int ii = 0; ii < 4; ii++) {
            float p0_ = __expf(s[ii][0] - 30.f);
            float p1_ = __expf(s[ii][1] - 30.f);
            float p2_ = __expf(s[ii][2] - 30.f);
            float p3_ = __expf(s[ii][3] - 30.f);
            lsum[ii] += (p0_ + p1_) + (p2_ + p3_);
            *(float4*)&ps[tm * 4 + ii][tn * 4] = make_float4(p0_, p1_, p2_, p3_);
        }

        // PV: acc[m][c] += P[m][n] * v[c][n], c in 4 chunks of 64
        for (int cc = 0; cc < 4; cc++) {
            __syncthreads(); // ps visible (cc=0) / vs consumers done (cc>0)
            for (int idx = t; idx < 4096; idx += 256) {
                int c = idx >> 6, n = idx & 63;
                vs[c][n] = v[((size_t)b * NC + cc * 64 + c) * NPIX + n0 + n];
            }
            __syncthreads();
            #pragma unroll 2
            for (int nn = 0; nn < 16; nn++) {
                int n4 = ((nn + tn) & 15) << 2;
                float4 pv[4], vv[4];
                #pragma unroll
                for (int ii = 0; ii < 4; ii++) pv[ii] = *(const float4*)&ps[tm * 4 + ii][n4];
                #pragma unroll
                for (int jj = 0; jj < 4; jj++) vv[jj] = *(const float4*)&vs[tn * 4 + jj][n4];
                #pragma unroll
                for (int ii = 0; ii < 4; ii++)
                    #pragma unroll
                    for (int jj = 0; jj < 4; jj++) {
                        float a = acc[ii][cc * 4 + jj];
                        a = fmaf(pv[ii].x, vv[jj].x, a);
                        a = fmaf(pv[ii].y, vv[jj].y, a);
                        a = fmaf(pv[ii].z, vv[jj].z, a);
                        a = fmaf(pv[ii].w, vv[jj].w, a);
                        acc[ii][cc * 4 + jj] = a;
                    }
            }
        }
    }

    // reduce row sums across the 16 tn threads
    #pragma unroll
    for (int ii = 0; ii < 4; ii++) red[tm * 4 + ii][tn] = lsum[ii];
    __syncthreads();
    if (t < 64) {
        float ss = 0.f;
        #pragma unroll
        for (int j = 0; j < 16; j++) ss += red[t][j];
        invl[t] = 1.0f / ss;
    }
    __syncthreads();
    float il[4];
    #pragma unroll
    for (int ii = 0; ii < 4; ii++) il[ii] = invl[tm * 4 + ii];

    // epilogue: out = acc/l + x, coalesced float4 over m
    const int mb = m0 + tm * 4;
    #pragma unroll
    for (int cc = 0; cc < 4; cc++)
        #pragma unroll
        for (int jj = 0; jj < 4; jj++) {
            int c = cc * 64 + tn * 4 + jj;
            size_t base = ((size_t)b * NC + c) * NPIX + mb;
            float4 xv = *(const float4*)&x[base];
            float4 o;
            o.x = fmaf(acc[0][cc * 4 + jj], il[0], xv.x);
            o.y = fmaf(acc[1][cc * 4 + jj], il[1], xv.y);
            o.z = fmaf(acc[2][cc * 4 + jj], il[2], xv.z);
            o.w = fmaf(acc[3][cc * 4 + jj], il[3], xv.w);
            *(float4*)&out[base] = o;
        }
}

extern "C" void kernel_launch(void* const* d_in, const int* in_sizes, int n_in,
                              void* d_out, int out_size, void* d_ws, size_t ws_size,
                              hipStream_t stream)
{
    const float* x  = (const float*)d_in[0];
    const float* Wq = (const float*)d_in[1];
    const float* bq = (const float*)d_in[2];
    const float* Wk = (const float*)d_in[3];
    const float* bk = (const float*)d_in[4];
    const float* Wv = (const float*)d_in[5];
    const float* bv = (const float*)d_in[6];
    float* outp = (float*)d_out;

    float* q_ws = (float*)d_ws;                       // [B][N][64]   8 MB
    float* k_ws = q_ws + (size_t)NB * NPIX * ND;      // [B][N][64]   8 MB
    float* v_ws = k_ws + (size_t)NB * NPIX * ND;      // [B][C][N]   32 MB

    dim3 blk(256);
    conv3x3_k<<<dim3(64, NB, 1), blk, 0, stream>>>(x, Wq, bq, q_ws, 1);
    conv3x3_k<<<dim3(64, NB, 1), blk, 0, stream>>>(x, Wk, bk, k_ws, 1);
    conv3x3_k<<<dim3(64, NB, 4), blk, 0, stream>>>(x, Wv, bv, v_ws, 0);
    attn_k<<<dim3(64, NB), blk, 0, stream>>>(q_ws, k_ws, v_ws, x, outp);
}

// Round 2
// 1505.536 us; speedup vs baseline: 1.9667x; 1.9667x over previous
//
#include <hip/hip_runtime.h>
#include <math.h>

#define NB   8
#define NC   256
#define ND   64
#define NPIX 4096
#define LSTR 72   // LDS row stride in bf16 elems: 144 B = 16B-aligned, +4-bank/row skew

typedef short bf16x8 __attribute__((ext_vector_type(8)));   // 8 bf16 (4 VGPRs)
typedef float f32x4  __attribute__((ext_vector_type(4)));

static __device__ __forceinline__ ushort f2bf(float f) {
    uint u = __float_as_uint(f);
    u += 0x7fffu + ((u >> 16) & 1u);      // round-to-nearest-even
    return (ushort)(u >> 16);
}
static __device__ __forceinline__ float bf2f(ushort h) {
    return __uint_as_float(((uint)h) << 16);
}

// ---------------------------------------------------------------------------
// conv3x3, SAME padding, fp32 compute. grid (64 rows h, B, Cout/64), block 256.
// layoutA=1: oh/ol = bf16 hi/lo planes, [b][p][64] (d-contig, q/k)
// layoutA=0: oh = bf16, [b][co][p] (p-contig, v)
// ---------------------------------------------------------------------------
__global__ __launch_bounds__(256) void conv3x3_k(
    const float* __restrict__ x, const float* __restrict__ Wt,
    const float* __restrict__ bias, ushort* __restrict__ oh,
    ushort* __restrict__ ol, int layoutA)
{
    const int h   = blockIdx.x;
    const int b   = blockIdx.y;
    const int co0 = blockIdx.z * 64;
    const int t   = threadIdx.x;
    const int tw  = t & 15;   // pixel group: w = 4*tw..+3
    const int tc  = t >> 4;   // co group:   co = tc*4..+3

    __shared__ float xs[3][8][68];   // [row r][ci][1+col], cols 0 & 65 zero pad
    __shared__ float ws[64][100];    // [co][ci*12 + k]

    float acc[4][4];
    #pragma unroll
    for (int i = 0; i < 4; i++)
        #pragma unroll
        for (int j = 0; j < 4; j++) acc[i][j] = 0.f;

    if (t < 24) { int r = t % 3, ci = t / 3; xs[r][ci][0] = 0.f; xs[r][ci][65] = 0.f; }

    for (int ci0 = 0; ci0 < NC; ci0 += 8) {
        __syncthreads();
        for (int idx = t; idx < 1536; idx += 256) {
            int col = idx & 63;
            int pr  = idx >> 6;
            int r = pr % 3, ci = pr / 3;
            int hs = h + r - 1;
            float val = 0.f;
            if (hs >= 0 && hs < 64)
                val = x[(((size_t)b * NC + ci0 + ci) * 64 + hs) * 64 + col];
            xs[r][ci][1 + col] = val;
        }
        for (int idx = t; idx < 4608; idx += 256) {
            int co = idx / 72, rem = idx - co * 72;
            int ci = rem / 9,  kk  = rem - ci * 9;
            ws[co][ci * 12 + kk] = Wt[((size_t)(co0 + co) * NC + ci0 + ci) * 9 + kk];
        }
        __syncthreads();
        #pragma unroll
        for (int ci = 0; ci < 8; ci++) {
            float xv[18];
            #pragma unroll
            for (int r = 0; r < 3; r++)
                #pragma unroll
                for (int c = 0; c < 6; c++)
                    xv[r * 6 + c] = xs[r][ci][4 * tw + c];
            #pragma unroll
            for (int j = 0; j < 4; j++) {
                const float* wr = &ws[tc * 4 + j][ci * 12];
                #pragma unroll
                for (int i = 0; i < 4; i++) {
                    float a = acc[i][j];
                    #pragma unroll
                    for (int r = 0; r < 3; r++)
                        #pragma unroll
                        for (int dx = 0; dx < 3; dx++)
                            a = fmaf(wr[r * 3 + dx], xv[r * 6 + i + dx], a);
                    acc[i][j] = a;
                }
            }
        }
    }

    float bj[4];
    #pragma unroll
    for (int j = 0; j < 4; j++) bj[j] = bias[co0 + tc * 4 + j];

    const int p0 = h * 64 + tw * 4;
    if (layoutA) {
        #pragma unroll
        for (int i = 0; i < 4; i++) {
            float v[4];
            ushort4 hv, lv;
            #pragma unroll
            for (int j = 0; j < 4; j++) v[j] = acc[i][j] + bj[j];
            hv.x = f2bf(v[0]); lv.x = f2bf(v[0] - bf2f(hv.x));
            hv.y = f2bf(v[1]); lv.y = f2bf(v[1] - bf2f(hv.y));
            hv.z = f2bf(v[2]); lv.z = f2bf(v[2] - bf2f(hv.z));
            hv.w = f2bf(v[3]); lv.w = f2bf(v[3] - bf2f(hv.w));
            const size_t g = ((size_t)b * NPIX + p0 + i) * 64 + tc * 4;
            *(ushort4*)&oh[g] = hv;
            *(ushort4*)&ol[g] = lv;
        }
    } else {
        #pragma unroll
        for (int j = 0; j < 4; j++) {
            float bb = bj[j];
            ushort4 pv;
            pv.x = f2bf(acc[0][j] + bb);
            pv.y = f2bf(acc[1][j] + bb);
            pv.z = f2bf(acc[2][j] + bb);
            pv.w = f2bf(acc[3][j] + bb);
            *(ushort4*)&oh[((size_t)b * NC + co0 + tc * 4 + j) * NPIX + p0] = pv;
        }
    }
}

// ---------------------------------------------------------------------------
// MFMA flash attention. grid (N/64, B), block 256 (4 waves).
// Per n0-tile of 64: S=Q.K^T (split bf16, 3 MFMA terms), P=exp(S-30)->LDS bf16,
// PV via MFMA, acc 64m x 256c in regs (wave w owns c 64w..64w+63).
// LDS: qs hi/lo | {ks hi/lo  UNION  vs} | ps | reduce  = 65.8 KB -> 2 blk/CU.
// ---------------------------------------------------------------------------
__global__ __launch_bounds__(256, 2) void attn_k(
    const ushort* __restrict__ qh, const ushort* __restrict__ ql,
    const ushort* __restrict__ kh, const ushort* __restrict__ kl,
    const ushort* __restrict__ vb, const float* __restrict__ x,
    float* __restrict__ out)
{
    const int b    = blockIdx.y;
    const int m0   = blockIdx.x * 64;
    const int t    = threadIdx.x;
    const int wave = t >> 6;
    const int lane = t & 63;
    const int quad = lane >> 4;
    const int l16  = lane & 15;

    __shared__ __align__(16) char smem[65792];
    ushort* sqh = (ushort*)(smem);            // [64][72] bf16
    ushort* sql = (ushort*)(smem + 9216);
    ushort* skh = (ushort*)(smem + 18432);    // [64][72]  (union with svs)
    ushort* skl = (ushort*)(smem + 27648);
    ushort* svs = (ushort*)(smem + 18432);    // [256][72] (overwrites ks after QK)
    ushort* sps = (ushort*)(smem + 55296);    // [64][72]
    float*  red = (float*)(smem + 64512);     // [64][4]
    float*  ivl = (float*)(smem + 65536);     // [64]

    // stage Q hi/lo (once)
    {
        const int r = t >> 2, dc = (t & 3) * 16;
        const size_t g = ((size_t)b * NPIX + m0 + r) * ND + dc;
        uint4 a0 = *(const uint4*)&qh[g];
        uint4 a1 = *(const uint4*)&qh[g + 8];
        *(uint4*)&sqh[r * LSTR + dc]     = a0;
        *(uint4*)&sqh[r * LSTR + dc + 8] = a1;
        uint4 b0 = *(const uint4*)&ql[g];
        uint4 b1 = *(const uint4*)&ql[g + 8];
        *(uint4*)&sql[r * LSTR + dc]     = b0;
        *(uint4*)&sql[r * LSTR + dc + 8] = b1;
    }

    f32x4 acc[16];
    #pragma unroll
    for (int i = 0; i < 16; i++) acc[i] = (f32x4){0.f, 0.f, 0.f, 0.f};
    float rsum = 0.f;
    const int rs_row = t & 63, rs_c = (t >> 6) * 16;

    for (int n0 = 0; n0 < NPIX; n0 += 64) {
        __syncthreads();   // prev PV reads of svs / rowsum reads of sps done; Q staged (iter 0)
        {   // stage K hi/lo into union region
            const int r = t >> 2, dc = (t & 3) * 16;
            const size_t g = ((size_t)b * NPIX + n0 + r) * ND + dc;
            uint4 a0 = *(const uint4*)&kh[g];
            uint4 a1 = *(const uint4*)&kh[g + 8];
            *(uint4*)&skh[r * LSTR + dc]     = a0;
            *(uint4*)&skh[r * LSTR + dc + 8] = a1;
            uint4 b0 = *(const uint4*)&kl[g];
            uint4 b1 = *(const uint4*)&kl[g + 8];
            *(uint4*)&skl[r * LSTR + dc]     = b0;
            *(uint4*)&skl[r * LSTR + dc + 8] = b1;
        }
        __syncthreads();

        // ---- QK: wave w computes S rows [16w,16w+16) x 64 n ----
        bf16x8 aqh[2], aql[2];
        const int am = 16 * wave + l16;
        #pragma unroll
        for (int ks = 0; ks < 2; ks++) {
            aqh[ks] = *(const bf16x8*)&sqh[am * LSTR + ks * 32 + quad * 8];
            aql[ks] = *(const bf16x8*)&sql[am * LSTR + ks * 32 + quad * 8];
        }
        #pragma unroll
        for (int nt = 0; nt < 4; nt++) {
            f32x4 s = {0.f, 0.f, 0.f, 0.f};
            const int bn = nt * 16 + l16;
            #pragma unroll
            for (int ks = 0; ks < 2; ks++) {
                bf16x8 bh = *(const bf16x8*)&skh[bn * LSTR + ks * 32 + quad * 8];
                bf16x8 bl = *(const bf16x8*)&skl[bn * LSTR + ks * 32 + quad * 8];
                s = __builtin_amdgcn_mfma_f32_16x16x32_bf16(aqh[ks], bh, s, 0, 0, 0);
                s = __builtin_amdgcn_mfma_f32_16x16x32_bf16(aql[ks], bh, s, 0, 0, 0);
                s = __builtin_amdgcn_mfma_f32_16x16x32_bf16(aqh[ks], bl, s, 0, 0, 0);
            }
            // exp + store P (C/D layout: col=l16, row=quad*4+r)
            #pragma unroll
            for (int r = 0; r < 4; r++) {
                float p = __expf(s[r] - 30.f);
                sps[(16 * wave + quad * 4 + r) * LSTR + nt * 16 + l16] = f2bf(p);
            }
        }
        __syncthreads();   // QK reads of skh/skl done; sps visible

        {   // stage V (overwrites ks region) + rowsum partial from rounded P
            const int c0 = t >> 2, ncs = (t & 3) * 16;
            #pragma unroll
            for (int cc = 0; cc < 4; cc++) {
                const int c = cc * 64 + c0;
                const size_t g = ((size_t)b * NC + c) * NPIX + n0 + ncs;
                uint4 a0 = *(const uint4*)&vb[g];
                uint4 a1 = *(const uint4*)&vb[g + 8];
                *(uint4*)&svs[c * LSTR + ncs]     = a0;
                *(uint4*)&svs[c * LSTR + ncs + 8] = a1;
            }
            uint4 p0 = *(const uint4*)&sps[rs_row * LSTR + rs_c];
            uint4 p1 = *(const uint4*)&sps[rs_row * LSTR + rs_c + 8];
            const ushort* pu0 = (const ushort*)&p0;
            const ushort* pu1 = (const ushort*)&p1;
            float ss = 0.f;
            #pragma unroll
            for (int i = 0; i < 8; i++) ss += bf2f(pu0[i]) + bf2f(pu1[i]);
            rsum += ss;
        }
        __syncthreads();

        // ---- PV: wave w owns c in [64w, 64w+64); all 64 m ----
        bf16x8 ap[4][2];
        #pragma unroll
        for (int ms = 0; ms < 4; ms++)
            #pragma unroll
            for (int ks = 0; ks < 2; ks++)
                ap[ms][ks] = *(const bf16x8*)&sps[(16 * ms + l16) * LSTR + ks * 32 + quad * 8];
        #pragma unroll
        for (int ct = 0; ct < 4; ct++) {
            const int c = 64 * wave + ct * 16 + l16;
            #pragma unroll
            for (int ks = 0; ks < 2; ks++) {
                bf16x8 bv = *(const bf16x8*)&svs[c * LSTR + ks * 32 + quad * 8];
                #pragma unroll
                for (int ms = 0; ms < 4; ms++)
                    acc[ms * 4 + ct] = __builtin_amdgcn_mfma_f32_16x16x32_bf16(
                        ap[ms][ks], bv, acc[ms * 4 + ct], 0, 0, 0);
            }
        }
    }

    // row-sum reduce across the 4 col-chunks
    red[(t & 63) * 4 + (t >> 6)] = rsum;
    __syncthreads();
    if (t < 64)
        ivl[t] = 1.f / (red[t * 4 + 0] + red[t * 4 + 1] + red[t * 4 + 2] + red[t * 4 + 3]);
    __syncthreads();

    // epilogue: out = acc/l + x ; lane holds col c, rows m = 16ms+quad*4+r (float4 over m)
    #pragma unroll
    for (int ms = 0; ms < 4; ms++) {
        const float il0 = ivl[16 * ms + quad * 4 + 0];
        const float il1 = ivl[16 * ms + quad * 4 + 1];
        const float il2 = ivl[16 * ms + quad * 4 + 2];
        const float il3 = ivl[16 * ms + quad * 4 + 3];
        const int m = m0 + 16 * ms + quad * 4;
        #pragma unroll
        for (int ct = 0; ct < 4; ct++) {
            const int c = 64 * wave + ct * 16 + l16;
            const size_t base = ((size_t)b * NC + c) * NPIX + m;
            float4 xv = *(const float4*)&x[base];
            f32x4 a = acc[ms * 4 + ct];
            float4 o;
            o.x = fmaf(a[0], il0, xv.x);
            o.y = fmaf(a[1], il1, xv.y);
            o.z = fmaf(a[2], il2, xv.z);
            o.w = fmaf(a[3], il3, xv.w);
            *(float4*)&out[base] = o;
        }
    }
}

extern "C" void kernel_launch(void* const* d_in, const int* in_sizes, int n_in,
                              void* d_out, int out_size, void* d_ws, size_t ws_size,
                              hipStream_t stream)
{
    const float* x  = (const float*)d_in[0];
    const float* Wq = (const float*)d_in[1];
    const float* bq = (const float*)d_in[2];
    const float* Wk = (const float*)d_in[3];
    const float* bk = (const float*)d_in[4];
    const float* Wv = (const float*)d_in[5];
    const float* bv = (const float*)d_in[6];
    float* outp = (float*)d_out;

    const size_t PLANE = (size_t)NB * NPIX * ND;   // 2M elems
    ushort* q_h = (ushort*)d_ws;
    ushort* q_l = q_h + PLANE;
    ushort* k_h = q_l + PLANE;
    ushort* k_l = k_h + PLANE;
    ushort* v_b = k_l + PLANE;                     // [B][C][N] bf16, 8M elems

    dim3 blk(256);
    conv3x3_k<<<dim3(64, NB, 1), blk, 0, stream>>>(x, Wq, bq, q_h, q_l, 1);
    conv3x3_k<<<dim3(64, NB, 1), blk, 0, stream>>>(x, Wk, bk, k_h, k_l, 1);
    conv3x3_k<<<dim3(64, NB, 4), blk, 0, stream>>>(x, Wv, bv, v_b, nullptr, 0);
    attn_k<<<dim3(64, NB), blk, 0, stream>>>(q_h, q_l, k_h, k_l, v_b, x, outp);
}

// Round 3
// 427.783 us; speedup vs baseline: 6.9215x; 3.5194x over previous
//
#include <hip/hip_runtime.h>
#include <math.h>

#define NB   8
#define NC   256
#define ND   64
#define NPIX 4096
#define LSTR 72   // attn LDS row stride (bf16 elems)

typedef short bf16x8 __attribute__((ext_vector_type(8)));   // 8 bf16 (4 VGPRs)
typedef float f32x4  __attribute__((ext_vector_type(4)));
typedef float f32x16 __attribute__((ext_vector_type(16)));

static __device__ __forceinline__ ushort f2bf(float f) {
    uint u = __float_as_uint(f);
    u += 0x7fffu + ((u >> 16) & 1u);      // round-to-nearest-even
    return (ushort)(u >> 16);
}
static __device__ __forceinline__ float bf2f(ushort h) {
    return __uint_as_float(((uint)h) << 16);
}

// ---------------------------------------------------------------------------
// transpose_x: x[b][c][p] f32 -> xt_h/xt_l [b][p][256] bf16 hi/lo.
// grid (64 ptile, 4 ctile, 8 b), block 256.
// ---------------------------------------------------------------------------
__global__ __launch_bounds__(256) void transpose_x(
    const float* __restrict__ x, ushort* __restrict__ xth, ushort* __restrict__ xtl)
{
    __shared__ float tile[64][68];
    const int t = threadIdx.x;
    const int p0 = blockIdx.x * 64, c0 = blockIdx.y * 64, b = blockIdx.z;

    const int cl = t >> 4, p4 = (t & 15) * 4;
    #pragma unroll
    for (int i = 0; i < 4; i++) {
        const int c = cl + 16 * i;
        *(float4*)&tile[c][p4] =
            *(const float4*)&x[((size_t)(b * NC + c0 + c)) * NPIX + p0 + p4];
    }
    __syncthreads();

    const int pl = t & 63, ch = t >> 6;   // ch: 16-c chunk
    float v[16];
    #pragma unroll
    for (int j = 0; j < 16; j++) v[j] = tile[ch * 16 + j][pl];
    ushort h[16], l[16];
    #pragma unroll
    for (int j = 0; j < 16; j++) {
        h[j] = f2bf(v[j]);
        l[j] = f2bf(v[j] - bf2f(h[j]));
    }
    const size_t o = ((size_t)(b * NPIX + p0 + pl)) * 256 + c0 + ch * 16;
    *(uint4*)&xth[o]     = *(uint4*)&h[0];
    *(uint4*)&xth[o + 8] = *(uint4*)&h[8];
    *(uint4*)&xtl[o]     = *(uint4*)&l[0];
    *(uint4*)&xtl[o + 8] = *(uint4*)&l[8];
}

// ---------------------------------------------------------------------------
// transpose_w: W[co][ci][3][3] f32 -> wt[rs][co][ci] bf16 (hi/lo for q,k).
// grid 384 (64 q co + 64 k co + 256 v co), block 256.
// ---------------------------------------------------------------------------
__global__ __launch_bounds__(256) void transpose_w(
    const float* __restrict__ Wq, const float* __restrict__ Wk,
    const float* __restrict__ Wv,
    ushort* __restrict__ qh, ushort* __restrict__ ql,
    ushort* __restrict__ kh, ushort* __restrict__ kl,
    ushort* __restrict__ vh)
{
    __shared__ float wb[2304];
    const int g = blockIdx.x, t = threadIdx.x;
    const float* src;
    ushort *dh, *dl;
    int co, Co, split;
    if (g < 64)       { src = Wq + (size_t)g * 2304; co = g;       Co = 64;  dh = qh; dl = ql; split = 1; }
    else if (g < 128) { src = Wk + (size_t)(g - 64) * 2304; co = g - 64; Co = 64; dh = kh; dl = kl; split = 1; }
    else              { src = Wv + (size_t)(g - 128) * 2304; co = g - 128; Co = 256; dh = vh; dl = nullptr; split = 0; }

    for (int i = t; i < 2304; i += 256) wb[i] = src[i];
    __syncthreads();
    for (int j = t; j < 2304; j += 256) {
        const int rs = j >> 8, ci = j & 255;
        const float v = wb[ci * 9 + rs];
        const ushort hv = f2bf(v);
        const size_t o = ((size_t)(rs * Co + co)) * 256 + ci;
        dh[o] = hv;
        if (split) dl[o] = f2bf(v - bf2f(hv));
    }
}

// ---------------------------------------------------------------------------
// MFMA conv (q/k, split-bf16 3-term). Block = 64co x 256pix (4 rows), wave=row.
// ci-chunk 16, ci padded to 24 in LDS (48-B stride: uniform banks + 16B align).
// grid (16 hq, 8 b, 2 {q,k}), dyn LDS 65920 B.
// ---------------------------------------------------------------------------
__global__ __launch_bounds__(256) void conv_split_k(
    const ushort* __restrict__ xth, const ushort* __restrict__ xtl,
    const ushort* __restrict__ wqh, const ushort* __restrict__ wql,
    const ushort* __restrict__ wkh, const ushort* __restrict__ wkl,
    const float* __restrict__ bq, const float* __restrict__ bk,
    ushort* __restrict__ qoh, ushort* __restrict__ qol,
    ushort* __restrict__ koh, ushort* __restrict__ kol)
{
    extern __shared__ char smem[];
    ushort* xsh = (ushort*)smem;                 // [6][66][24]
    ushort* xsl = xsh + 6 * 66 * 24;             // [6][66][24]
    ushort* wsp = xsl + 6 * 66 * 24;             // [9][64][24] (one w-plane at a time)
    float*  sbias = (float*)(wsp + 9 * 64 * 24); // [64]

    const int hq = blockIdx.x, b = blockIdx.y, ct = blockIdx.z;
    const ushort* wth = ct ? wkh : wqh;
    const ushort* wtl = ct ? wkl : wql;
    const float*  bias = ct ? bk : bq;
    ushort* outh = ct ? koh : qoh;
    ushort* outl = ct ? kol : qol;

    const int t = threadIdx.x;
    const int wv = t >> 6, lane = t & 63;
    const int l31 = lane & 31, khl = lane >> 5;
    const int lanebase = l31 * 24 + khl * 8;
    const int h = hq * 4 + wv;

    if (t < 64) sbias[t] = bias[t];
    // zero halo cols 0 and 65 (both planes), ci 0..15
    for (int i = t; i < 384; i += 256) {
        const int p = i / 192, r2 = i % 192;
        const int row = r2 / 32, e = (r2 % 32) / 16, ci = r2 & 15;
        (p ? xsl : xsh)[(row * 66 + e * 65) * 24 + ci] = 0;
    }

    f32x16 a00 = {0}, a01 = {0}, a10 = {0}, a11 = {0};  // [ms(co)][ns(pix)]

    for (int ch = 0; ch < 16; ch++) {
        __syncthreads();
        const int ci0 = ch * 16;
        // stage x hi+lo: rows hq*4-1 .. hq*4+4
        #pragma unroll
        for (int pl2 = 0; pl2 < 2; pl2++) {
            const ushort* src = pl2 ? xtl : xth;
            ushort* dst = pl2 ? xsl : xsh;
            #pragma unroll
            for (int i = 0; i < 3; i++) {
                const int a = i * 256 + t;
                const int cih = a & 1, col = (a >> 1) & 63, row = a >> 7;
                const int hs = hq * 4 + row - 1;
                uint4 val = {0, 0, 0, 0};
                if (hs >= 0 && hs < 64)
                    val = *(const uint4*)&src[((size_t)(b * NPIX + hs * 64 + col)) * 256 + ci0 + cih * 8];
                *(uint4*)&dst[(row * 66 + 1 + col) * 24 + cih * 8] = val;
            }
        }
        // stage w hi
        #pragma unroll
        for (int i = 0; i < 5; i++) {
            const int a = i * 256 + t;
            if (a < 1152) {
                const int cih = a & 1, co = (a >> 1) & 63, rs = a >> 7;
                uint4 wv4 = *(const uint4*)&wth[((size_t)(rs * 64 + co)) * 256 + ci0 + cih * 8];
                *(uint4*)&wsp[(rs * 64 + co) * 24 + cih * 8] = wv4;
            }
        }
        __syncthreads();
        // pass0: (wh.xh) + (wh.xl)
        #pragma unroll
        for (int rs = 0; rs < 9; rs++) {
            const int r = rs / 3, s = rs % 3;
            bf16x8 A0 = *(const bf16x8*)&wsp[rs * 1536 + lanebase];
            bf16x8 A1 = *(const bf16x8*)&wsp[rs * 1536 + 768 + lanebase];
            const int xo = ((wv + r) * 66 + s) * 24 + lanebase;
            bf16x8 B0h = *(const bf16x8*)&xsh[xo];
            bf16x8 B1h = *(const bf16x8*)&xsh[xo + 768];
            bf16x8 B0l = *(const bf16x8*)&xsl[xo];
            bf16x8 B1l = *(const bf16x8*)&xsl[xo + 768];
            a00 = __builtin_amdgcn_mfma_f32_32x32x16_bf16(A0, B0h, a00, 0, 0, 0);
            a01 = __builtin_amdgcn_mfma_f32_32x32x16_bf16(A0, B1h, a01, 0, 0, 0);
            a10 = __builtin_amdgcn_mfma_f32_32x32x16_bf16(A1, B0h, a10, 0, 0, 0);
            a11 = __builtin_amdgcn_mfma_f32_32x32x16_bf16(A1, B1h, a11, 0, 0, 0);
            a00 = __builtin_amdgcn_mfma_f32_32x32x16_bf16(A0, B0l, a00, 0, 0, 0);
            a01 = __builtin_amdgcn_mfma_f32_32x32x16_bf16(A0, B1l, a01, 0, 0, 0);
            a10 = __builtin_amdgcn_mfma_f32_32x32x16_bf16(A1, B0l, a10, 0, 0, 0);
            a11 = __builtin_amdgcn_mfma_f32_32x32x16_bf16(A1, B1l, a11, 0, 0, 0);
        }
        __syncthreads();
        // stage w lo
        #pragma unroll
        for (int i = 0; i < 5; i++) {
            const int a = i * 256 + t;
            if (a < 1152) {
                const int cih = a & 1, co = (a >> 1) & 63, rs = a >> 7;
                uint4 wv4 = *(const uint4*)&wtl[((size_t)(rs * 64 + co)) * 256 + ci0 + cih * 8];
                *(uint4*)&wsp[(rs * 64 + co) * 24 + cih * 8] = wv4;
            }
        }
        __syncthreads();
        // pass1: (wl.xh)
        #pragma unroll
        for (int rs = 0; rs < 9; rs++) {
            const int r = rs / 3, s = rs % 3;
            bf16x8 A0 = *(const bf16x8*)&wsp[rs * 1536 + lanebase];
            bf16x8 A1 = *(const bf16x8*)&wsp[rs * 1536 + 768 + lanebase];
            const int xo = ((wv + r) * 66 + s) * 24 + lanebase;
            bf16x8 B0h = *(const bf16x8*)&xsh[xo];
            bf16x8 B1h = *(const bf16x8*)&xsh[xo + 768];
            a00 = __builtin_amdgcn_mfma_f32_32x32x16_bf16(A0, B0h, a00, 0, 0, 0);
            a01 = __builtin_amdgcn_mfma_f32_32x32x16_bf16(A0, B1h, a01, 0, 0, 0);
            a10 = __builtin_amdgcn_mfma_f32_32x32x16_bf16(A1, B0h, a10, 0, 0, 0);
            a11 = __builtin_amdgcn_mfma_f32_32x32x16_bf16(A1, B1h, a11, 0, 0, 0);
        }
    }

    // epilogue: C/D col = pixel (l31 within ns), row = co = (reg&3)+8*(reg>>2)+4*khl
    const float4* sb4 = (const float4*)sbias;
    #pragma unroll
    for (int ms = 0; ms < 2; ms++)
        #pragma unroll
        for (int ns = 0; ns < 2; ns++) {
            const f32x16 av = ms ? (ns ? a11 : a10) : (ns ? a01 : a00);
            const int p = h * 64 + ns * 32 + l31;
            #pragma unroll
            for (int g = 0; g < 4; g++) {
                const float4 bi = sb4[ms * 8 + 2 * g + khl];
                float v0 = av[4 * g + 0] + bi.x;
                float v1 = av[4 * g + 1] + bi.y;
                float v2 = av[4 * g + 2] + bi.z;
                float v3 = av[4 * g + 3] + bi.w;
                ushort4 hv, lv;
                hv.x = f2bf(v0); lv.x = f2bf(v0 - bf2f(hv.x));
                hv.y = f2bf(v1); lv.y = f2bf(v1 - bf2f(hv.y));
                hv.z = f2bf(v2); lv.z = f2bf(v2 - bf2f(hv.z));
                hv.w = f2bf(v3); lv.w = f2bf(v3 - bf2f(hv.w));
                const size_t o = ((size_t)(b * NPIX + p)) * 64 + ms * 32 + 8 * g + 4 * khl;
                *(ushort4*)&outh[o] = hv;
                *(ushort4*)&outl[o] = lv;
            }
        }
}

// ---------------------------------------------------------------------------
// MFMA conv (v, plain bf16). A = x (m=pixel), B = w (n=co).
// grid (16 hq, 8 b, 4 cotile), dyn LDS 46912 B.
// ---------------------------------------------------------------------------
__global__ __launch_bounds__(256) void conv_v_k(
    const ushort* __restrict__ xth, const ushort* __restrict__ wtv,
    const float* __restrict__ bv, ushort* __restrict__ vout)
{
    extern __shared__ char smem[];
    ushort* xsh = (ushort*)smem;                 // [6][66][24]
    ushort* wsp = xsh + 6 * 66 * 24;             // [9][64][24]
    float*  sbias = (float*)(wsp + 9 * 64 * 24); // [64]

    const int hq = blockIdx.x, b = blockIdx.y, co0 = blockIdx.z * 64;
    const int t = threadIdx.x;
    const int wv = t >> 6, lane = t & 63;
    const int l31 = lane & 31, khl = lane >> 5;
    const int lanebase = l31 * 24 + khl * 8;
    const int h = hq * 4 + wv;

    if (t < 64) sbias[t] = bv[co0 + t];
    for (int i = t; i < 192; i += 256) {
        const int row = i / 32, e = (i % 32) / 16, ci = i & 15;
        xsh[(row * 66 + e * 65) * 24 + ci] = 0;
    }

    f32x16 a00 = {0}, a01 = {0}, a10 = {0}, a11 = {0};  // [ms(pix)][ns(co)]

    for (int ch = 0; ch < 16; ch++) {
        __syncthreads();
        const int ci0 = ch * 16;
        #pragma unroll
        for (int i = 0; i < 3; i++) {
            const int a = i * 256 + t;
            const int cih = a & 1, col = (a >> 1) & 63, row = a >> 7;
            const int hs = hq * 4 + row - 1;
            uint4 val = {0, 0, 0, 0};
            if (hs >= 0 && hs < 64)
                val = *(const uint4*)&xth[((size_t)(b * NPIX + hs * 64 + col)) * 256 + ci0 + cih * 8];
            *(uint4*)&xsh[(row * 66 + 1 + col) * 24 + cih * 8] = val;
        }
        #pragma unroll
        for (int i = 0; i < 5; i++) {
            const int a = i * 256 + t;
            if (a < 1152) {
                const int cih = a & 1, co = (a >> 1) & 63, rs = a >> 7;
                uint4 wv4 = *(const uint4*)&wtv[((size_t)(rs * 256 + co0 + co)) * 256 + ci0 + cih * 8];
                *(uint4*)&wsp[(rs * 64 + co) * 24 + cih * 8] = wv4;
            }
        }
        __syncthreads();
        #pragma unroll
        for (int rs = 0; rs < 9; rs++) {
            const int r = rs / 3, s = rs % 3;
            const int xo = ((wv + r) * 66 + s) * 24 + lanebase;
            bf16x8 A0 = *(const bf16x8*)&xsh[xo];          // pixels ms=0
            bf16x8 A1 = *(const bf16x8*)&xsh[xo + 768];    // pixels ms=1
            bf16x8 B0 = *(const bf16x8*)&wsp[rs * 1536 + lanebase];
            bf16x8 B1 = *(const bf16x8*)&wsp[rs * 1536 + 768 + lanebase];
            a00 = __builtin_amdgcn_mfma_f32_32x32x16_bf16(A0, B0, a00, 0, 0, 0);
            a01 = __builtin_amdgcn_mfma_f32_32x32x16_bf16(A0, B1, a01, 0, 0, 0);
            a10 = __builtin_amdgcn_mfma_f32_32x32x16_bf16(A1, B0, a10, 0, 0, 0);
            a11 = __builtin_amdgcn_mfma_f32_32x32x16_bf16(A1, B1, a11, 0, 0, 0);
        }
    }

    // epilogue: C/D col = co (l31), row = pixel = (reg&3)+8*(reg>>2)+4*khl
    #pragma unroll
    for (int ns = 0; ns < 2; ns++) {
        const int co = co0 + ns * 32 + l31;
        const float bi = sbias[ns * 32 + l31];
        #pragma unroll
        for (int ms = 0; ms < 2; ms++) {
            const f32x16 av = ms ? (ns ? a11 : a10) : (ns ? a01 : a00);
            #pragma unroll
            for (int g = 0; g < 4; g++) {
                const int p = h * 64 + ms * 32 + 8 * g + 4 * khl;
                ushort4 ov;
                ov.x = f2bf(av[4 * g + 0] + bi);
                ov.y = f2bf(av[4 * g + 1] + bi);
                ov.z = f2bf(av[4 * g + 2] + bi);
                ov.w = f2bf(av[4 * g + 3] + bi);
                *(ushort4*)&vout[((size_t)(b * NC + co)) * NPIX + p] = ov;
            }
        }
    }
}

// ---------------------------------------------------------------------------
// MFMA flash attention (unchanged from R1). grid (N/64, B), block 256.
// ---------------------------------------------------------------------------
__global__ __launch_bounds__(256, 2) void attn_k(
    const ushort* __restrict__ qh, const ushort* __restrict__ ql,
    const ushort* __restrict__ kh, const ushort* __restrict__ kl,
    const ushort* __restrict__ vb, const float* __restrict__ x,
    float* __restrict__ out)
{
    const int b    = blockIdx.y;
    const int m0   = blockIdx.x * 64;
    const int t    = threadIdx.x;
    const int wave = t >> 6;
    const int lane = t & 63;
    const int quad = lane >> 4;
    const int l16  = lane & 15;

    __shared__ __align__(16) char smem[65792];
    ushort* sqh = (ushort*)(smem);
    ushort* sql = (ushort*)(smem + 9216);
    ushort* skh = (ushort*)(smem + 18432);
    ushort* skl = (ushort*)(smem + 27648);
    ushort* svs = (ushort*)(smem + 18432);
    ushort* sps = (ushort*)(smem + 55296);
    float*  red = (float*)(smem + 64512);
    float*  ivl = (float*)(smem + 65536);

    {
        const int r = t >> 2, dc = (t & 3) * 16;
        const size_t g = ((size_t)b * NPIX + m0 + r) * ND + dc;
        uint4 a0 = *(const uint4*)&qh[g];
        uint4 a1 = *(const uint4*)&qh[g + 8];
        *(uint4*)&sqh[r * LSTR + dc]     = a0;
        *(uint4*)&sqh[r * LSTR + dc + 8] = a1;
        uint4 b0 = *(const uint4*)&ql[g];
        uint4 b1 = *(const uint4*)&ql[g + 8];
        *(uint4*)&sql[r * LSTR + dc]     = b0;
        *(uint4*)&sql[r * LSTR + dc + 8] = b1;
    }

    f32x4 acc[16];
    #pragma unroll
    for (int i = 0; i < 16; i++) acc[i] = (f32x4){0.f, 0.f, 0.f, 0.f};
    float rsum = 0.f;
    const int rs_row = t & 63, rs_c = (t >> 6) * 16;

    for (int n0 = 0; n0 < NPIX; n0 += 64) {
        __syncthreads();
        {
            const int r = t >> 2, dc = (t & 3) * 16;
            const size_t g = ((size_t)b * NPIX + n0 + r) * ND + dc;
            uint4 a0 = *(const uint4*)&kh[g];
            uint4 a1 = *(const uint4*)&kh[g + 8];
            *(uint4*)&skh[r * LSTR + dc]     = a0;
            *(uint4*)&skh[r * LSTR + dc + 8] = a1;
            uint4 b0 = *(const uint4*)&kl[g];
            uint4 b1 = *(const uint4*)&kl[g + 8];
            *(uint4*)&skl[r * LSTR + dc]     = b0;
            *(uint4*)&skl[r * LSTR + dc + 8] = b1;
        }
        __syncthreads();

        bf16x8 aqh[2], aql[2];
        const int am = 16 * wave + l16;
        #pragma unroll
        for (int ks = 0; ks < 2; ks++) {
            aqh[ks] = *(const bf16x8*)&sqh[am * LSTR + ks * 32 + quad * 8];
            aql[ks] = *(const bf16x8*)&sql[am * LSTR + ks * 32 + quad * 8];
        }
        #pragma unroll
        for (int nt = 0; nt < 4; nt++) {
            f32x4 s = {0.f, 0.f, 0.f, 0.f};
            const int bn = nt * 16 + l16;
            #pragma unroll
            for (int ks = 0; ks < 2; ks++) {
                bf16x8 bh = *(const bf16x8*)&skh[bn * LSTR + ks * 32 + quad * 8];
                bf16x8 bl = *(const bf16x8*)&skl[bn * LSTR + ks * 32 + quad * 8];
                s = __builtin_amdgcn_mfma_f32_16x16x32_bf16(aqh[ks], bh, s, 0, 0, 0);
                s = __builtin_amdgcn_mfma_f32_16x16x32_bf16(aql[ks], bh, s, 0, 0, 0);
                s = __builtin_amdgcn_mfma_f32_16x16x32_bf16(aqh[ks], bl, s, 0, 0, 0);
            }
            #pragma unroll
            for (int r = 0; r < 4; r++) {
                float p = __expf(s[r] - 30.f);
                sps[(16 * wave + quad * 4 + r) * LSTR + nt * 16 + l16] = f2bf(p);
            }
        }
        __syncthreads();

        {
            const int c0 = t >> 2, ncs = (t & 3) * 16;
            #pragma unroll
            for (int cc = 0; cc < 4; cc++) {
                const int c = cc * 64 + c0;
                const size_t g = ((size_t)b * NC + c) * NPIX + n0 + ncs;
                uint4 a0 = *(const uint4*)&vb[g];
                uint4 a1 = *(const uint4*)&vb[g + 8];
                *(uint4*)&svs[c * LSTR + ncs]     = a0;
                *(uint4*)&svs[c * LSTR + ncs + 8] = a1;
            }
            uint4 p0 = *(const uint4*)&sps[rs_row * LSTR + rs_c];
            uint4 p1 = *(const uint4*)&sps[rs_row * LSTR + rs_c + 8];
            const ushort* pu0 = (const ushort*)&p0;
            const ushort* pu1 = (const ushort*)&p1;
            float ss = 0.f;
            #pragma unroll
            for (int i = 0; i < 8; i++) ss += bf2f(pu0[i]) + bf2f(pu1[i]);
            rsum += ss;
        }
        __syncthreads();

        bf16x8 ap[4][2];
        #pragma unroll
        for (int ms = 0; ms < 4; ms++)
            #pragma unroll
            for (int ks = 0; ks < 2; ks++)
                ap[ms][ks] = *(const bf16x8*)&sps[(16 * ms + l16) * LSTR + ks * 32 + quad * 8];
        #pragma unroll
        for (int ct = 0; ct < 4; ct++) {
            const int c = 64 * wave + ct * 16 + l16;
            #pragma unroll
            for (int ks = 0; ks < 2; ks++) {
                bf16x8 bv = *(const bf16x8*)&svs[c * LSTR + ks * 32 + quad * 8];
                #pragma unroll
                for (int ms = 0; ms < 4; ms++)
                    acc[ms * 4 + ct] = __builtin_amdgcn_mfma_f32_16x16x32_bf16(
                        ap[ms][ks], bv, acc[ms * 4 + ct], 0, 0, 0);
            }
        }
    }

    red[(t & 63) * 4 + (t >> 6)] = rsum;
    __syncthreads();
    if (t < 64)
        ivl[t] = 1.f / (red[t * 4 + 0] + red[t * 4 + 1] + red[t * 4 + 2] + red[t * 4 + 3]);
    __syncthreads();

    #pragma unroll
    for (int ms = 0; ms < 4; ms++) {
        const float il0 = ivl[16 * ms + quad * 4 + 0];
        const float il1 = ivl[16 * ms + quad * 4 + 1];
        const float il2 = ivl[16 * ms + quad * 4 + 2];
        const float il3 = ivl[16 * ms + quad * 4 + 3];
        const int m = m0 + 16 * ms + quad * 4;
        #pragma unroll
        for (int ct = 0; ct < 4; ct++) {
            const int c = 64 * wave + ct * 16 + l16;
            const size_t base = ((size_t)b * NC + c) * NPIX + m;
            float4 xv = *(const float4*)&x[base];
            f32x4 a = acc[ms * 4 + ct];
            float4 o;
            o.x = fmaf(a[0], il0, xv.x);
            o.y = fmaf(a[1], il1, xv.y);
            o.z = fmaf(a[2], il2, xv.z);
            o.w = fmaf(a[3], il3, xv.w);
            *(float4*)&out[base] = o;
        }
    }
}

extern "C" void kernel_launch(void* const* d_in, const int* in_sizes, int n_in,
                              void* d_out, int out_size, void* d_ws, size_t ws_size,
                              hipStream_t stream)
{
    const float* x  = (const float*)d_in[0];
    const float* Wq = (const float*)d_in[1];
    const float* bq = (const float*)d_in[2];
    const float* Wk = (const float*)d_in[3];
    const float* bk = (const float*)d_in[4];
    const float* Wv = (const float*)d_in[5];
    const float* bv = (const float*)d_in[6];
    float* outp = (float*)d_out;

    const size_t XT = (size_t)NB * NPIX * 256;   // 8,388,608
    const size_t QK = (size_t)NB * NPIX * ND;    // 2,097,152
    ushort* xt_h = (ushort*)d_ws;
    ushort* xt_l = xt_h + XT;
    ushort* v_b  = xt_l;              // alias: conv_v writes after conv_split's last read
    ushort* q_h  = xt_l + XT;
    ushort* q_l  = q_h + QK;
    ushort* k_h  = q_l + QK;
    ushort* k_l  = k_h + QK;
    ushort* wtq_h = k_l + QK;         // 9*64*256 = 147456 each
    ushort* wtq_l = wtq_h + 147456;
    ushort* wtk_h = wtq_l + 147456;
    ushort* wtk_l = wtk_h + 147456;
    ushort* wtv_h = wtk_l + 147456;   // 9*256*256 = 589824

    dim3 blk(256);
    transpose_x<<<dim3(64, 4, NB), blk, 0, stream>>>(x, xt_h, xt_l);
    transpose_w<<<dim3(384), blk, 0, stream>>>(Wq, Wk, Wv, wtq_h, wtq_l, wtk_h, wtk_l, wtv_h);
    conv_split_k<<<dim3(16, NB, 2), blk, 65920, stream>>>(
        xt_h, xt_l, wtq_h, wtq_l, wtk_h, wtk_l, bq, bk, q_h, q_l, k_h, k_l);
    conv_v_k<<<dim3(16, NB, 4), blk, 46912, stream>>>(xt_h, wtv_h, bv, v_b);
    attn_k<<<dim3(64, NB), blk, 0, stream>>>(q_h, q_l, k_h, k_l, v_b, x, outp);
}